// Round 3
// baseline (139.887 us; speedup 1.0000x reference)
//
#include <hip/hip_runtime.h>
#include <math.h>

#define HH 1024
#define WW 1024
#define OH 1020
#define OW 1020
#define KS 5
#define CHUNK 128
#define NCHUNK 8      // ceil(1020/128)
#define TPB 256
#define XTILES 4      // 4*256 = 1024 >= 1020
#define NIMG 48       // B*C = 16*3
#define CCH 3

// GK = 5 * sqrt(2*pi) * sigma^2, sigma=2 (rounded to nearest f32 at compile time)
#define GKC 50.132565492620004f
#define EPSC 1e-6f
// Windows with |box_sum| below this get their sum recomputed in replicated
// numpy-f32 order (the ratio is rounding-noise-sensitive there). ~1600 of 1e8.
#define RECOMP_T 1e-4f

// Candidate order A: numpy sliding_window_view(x,(5,5),axis=(2,3)).sum((-2,-1)):
// inner (contiguous col) axis n=5 < 8 -> sequential fold; outer (row) axis ->
// sequential left-fold of the row sums.
__device__ __forceinline__ float win25_np(const float* __restrict__ p) {
    float s = 0.0f;
    #pragma unroll
    for (int r = 0; r < KS; ++r) {
        const float* q = p + (size_t)r * WW;
        float t = q[0];
        t += q[1]; t += q[2]; t += q[3]; t += q[4];
        s += t;   // r=0: 0+t0 is exact in f32
    }
    return s;
}

// Fast separable path (order-insensitive regime |s| >= RECOMP_T)
__device__ __forceinline__ void row_sums(const float* __restrict__ row,
                                         float& s, float& a) {
    float v0 = row[0], v1 = row[1], v2 = row[2], v3 = row[3], v4 = row[4];
    s = ((v0 + v1) + (v2 + v3)) + v4;
    a = ((fabsf(v0) + fabsf(v1)) + (fabsf(v2) + fabsf(v3))) + fabsf(v4);
}

__global__ __launch_bounds__(TPB)
void rtv_partial(const float* __restrict__ gh, const float* __restrict__ gw,
                 const float* __restrict__ gam, double* __restrict__ partial)
{
    const int x   = blockIdx.x * TPB + (int)threadIdx.x;  // output column
    const int img = blockIdx.z;                            // b*C + c
    const int y0  = blockIdx.y * CHUNK;                    // first output row
    const int y1  = min(y0 + CHUNK, OH);

    double acc = 0.0;

    if (x < OW) {
        const float* __restrict__ ph = gh + (size_t)img * HH * WW;
        const float* __restrict__ pw = gw + (size_t)img * HH * WW;

        float sh[KS], ah[KS], sw[KS], aw[KS];
        #pragma unroll
        for (int i = 0; i < KS - 1; ++i) {
            row_sums(ph + (size_t)(y0 + i) * WW + x, sh[i], ah[i]);
            row_sums(pw + (size_t)(y0 + i) * WW + x, sw[i], aw[i]);
        }

        for (int y = y0; y < y1; ++y) {
            row_sums(ph + (size_t)(y + 4) * WW + x, sh[KS - 1], ah[KS - 1]);
            row_sums(pw + (size_t)(y + 4) * WW + x, sw[KS - 1], aw[KS - 1]);

            float vs_h = ((sh[0] + sh[1]) + (sh[2] + sh[3])) + sh[4];
            float va_h = ((ah[0] + ah[1]) + (ah[2] + ah[3])) + ah[4];
            float vs_w = ((sw[0] + sw[1]) + (sw[2] + sw[3])) + sw[4];
            float va_w = ((aw[0] + aw[1]) + (aw[2] + aw[3])) + aw[4];

            float den_h, den_w;
            if (__builtin_expect(fabsf(vs_h) < RECOMP_T, 0)) {
                float s32 = win25_np(ph + (size_t)y * WW + x);
                den_h = fabsf(GKC * s32) + EPSC;   // np: |GK*box| + eps
            } else {
                den_h = fabsf(GKC * vs_h) + EPSC;
            }
            if (__builtin_expect(fabsf(vs_w) < RECOMP_T, 0)) {
                float s32 = win25_np(pw + (size_t)y * WW + x);
                den_w = fabsf(GKC * s32) + EPSC;
            } else {
                den_w = fabsf(GKC * vs_w) + EPSC;
            }

            acc += (double)((GKC * va_h) / den_h)
                 + (double)((GKC * va_w) / den_w);

            #pragma unroll
            for (int i = 0; i < KS - 1; ++i) {
                sh[i] = sh[i + 1]; ah[i] = ah[i + 1];
                sw[i] = sw[i + 1]; aw[i] = aw[i + 1];
            }
        }
    }

    // weight: exp(1 - gam[b]), constant per image
    const int b = img / CCH;
    acc *= (double)expf(1.0f - gam[b]);

    // block reduction: wave shuffle then LDS, in f64
    #pragma unroll
    for (int off = 32; off >= 1; off >>= 1)
        acc += __shfl_down(acc, off, 64);

    __shared__ double red[TPB / 64];
    const int lane = threadIdx.x & 63;
    const int wid  = threadIdx.x >> 6;
    if (lane == 0) red[wid] = acc;
    __syncthreads();
    if (threadIdx.x == 0) {
        double t = (red[0] + red[1]) + (red[2] + red[3]);
        partial[((size_t)blockIdx.z * gridDim.y + blockIdx.y) * gridDim.x
                + blockIdx.x] = t;
    }
}

__global__ __launch_bounds__(256)
void rtv_reduce(const double* __restrict__ partial, int n,
                float* __restrict__ out)
{
    double acc = 0.0;
    for (int i = threadIdx.x; i < n; i += 256)
        acc += partial[i];

    #pragma unroll
    for (int off = 32; off >= 1; off >>= 1)
        acc += __shfl_down(acc, off, 64);

    __shared__ double red[4];
    const int lane = threadIdx.x & 63;
    const int wid  = threadIdx.x >> 6;
    if (lane == 0) red[wid] = acc;
    __syncthreads();
    if (threadIdx.x == 0) {
        double tot = (red[0] + red[1]) + (red[2] + red[3]);
        // mean over B*C*OH*OW = 48 * 1020*1020 elements (both terms share N)
        const double N = 48.0 * 1040400.0;
        out[0] = (float)(tot / N);
    }
}

extern "C" void kernel_launch(void* const* d_in, const int* in_sizes, int n_in,
                              void* d_out, int out_size, void* d_ws, size_t ws_size,
                              hipStream_t stream) {
    const float* gh  = (const float*)d_in[0];
    const float* gw  = (const float*)d_in[1];
    const float* gam = (const float*)d_in[2];
    float* out = (float*)d_out;
    double* ws = (double*)d_ws;

    dim3 grid(XTILES, NCHUNK, NIMG);
    rtv_partial<<<grid, TPB, 0, stream>>>(gh, gw, gam, ws);

    const int nparts = XTILES * NCHUNK * NIMG;   // 1536
    rtv_reduce<<<1, 256, 0, stream>>>(ws, nparts, out);
}

// Round 4
// 101.932 us; speedup vs baseline: 1.3723x; 1.3723x over previous
//
#include <hip/hip_runtime.h>
#include <math.h>

#define HH 1024
#define WW 1024
#define OH 1020
#define OW 1020
#define KS 5
#define CHUNK 64
#define NCHUNK 16     // 16*64 >= 1020 (last chunk 60 rows)
#define TPB 256
#define T 4           // output columns per thread; 256*4 = 1024 covers W
#define NIMG 48       // B*C = 16*3
#define CCH 3

// GK = 5 * sqrt(2*pi) * sigma^2, sigma=2
#define GKC 50.132565492620004f
#define EPSC 1e-6f
// Windows with |box_sum| below this get their sum recomputed in replicated
// numpy-f32 order (the ratio is rounding-noise-sensitive there).
#define RECOMP_T 1e-4f

// numpy order: inner (contiguous col) axis n=5 -> sequential fold; outer (row)
// axis -> sequential left-fold of the row sums. KEEP IDENTICAL (R3 passed).
__device__ __forceinline__ float win25_np(const float* __restrict__ p) {
    float s = 0.0f;
    #pragma unroll
    for (int r = 0; r < KS; ++r) {
        const float* q = p + (size_t)r * WW;
        float t = q[0];
        t += q[1]; t += q[2]; t += q[3]; t += q[4];
        s += t;
    }
    return s;
}

// Load 8 consecutive floats (two float4), produce 4 horizontal 5-window sums
// (signed s[0..3], abs a[0..3]) shared incrementally across the 4 outputs.
__device__ __forceinline__ void load_row(const float* __restrict__ row,
                                         float* __restrict__ s,
                                         float* __restrict__ a) {
    float4 u = *reinterpret_cast<const float4*>(row);
    float4 v = *reinterpret_cast<const float4*>(row + 4);
    float s0 = ((u.x + u.y) + (u.z + u.w)) + v.x;
    s[0] = s0;
    s[1] = s0   - u.x + v.y;
    s[2] = s[1] - u.y + v.z;
    s[3] = s[2] - u.z + v.w;
    float p0 = fabsf(u.x), p1 = fabsf(u.y), p2 = fabsf(u.z), p3 = fabsf(u.w);
    float q0 = fabsf(v.x), q1 = fabsf(v.y), q2 = fabsf(v.z), q3 = fabsf(v.w);
    float t0 = ((p0 + p1) + (p2 + p3)) + q0;
    a[0] = t0;
    a[1] = t0   - p0 + q1;
    a[2] = a[1] - p1 + q2;
    a[3] = a[2] - p2 + q3;
}

__global__ __launch_bounds__(TPB)
void rtv_partial(const float* __restrict__ gh, const float* __restrict__ gw,
                 const float* __restrict__ gam, double* __restrict__ partial)
{
    const int x0  = (int)threadIdx.x * T;   // first output column of this thread
    const int img = blockIdx.z;             // b*C + c
    const int y0  = blockIdx.y * CHUNK;     // first output row
    const int y1  = min(y0 + CHUNK, OH);

    float acc = 0.0f;

    if (x0 < OW) {                          // thread 255 (x0=1020) inactive
        const float* __restrict__ ph = gh + (size_t)img * HH * WW;
        const float* __restrict__ pw = gw + (size_t)img * HH * WW;

        // 5-slot rings of horizontal window sums for T outputs
        float hs[KS][T], ha[KS][T], vws[KS][T], vwa[KS][T];
        #pragma unroll
        for (int i = 0; i < KS - 1; ++i) {
            load_row(ph + (size_t)(y0 + i) * WW + x0, hs[i], ha[i]);
            load_row(pw + (size_t)(y0 + i) * WW + x0, vws[i], vwa[i]);
        }

        for (int yb = y0; yb < y1; yb += KS) {
            #pragma unroll
            for (int k = 0; k < KS; ++k) {
                const int y = yb + k;
                if (y < y1) {
                    const int snew = (k + 4) % KS;     // static after unroll
                    load_row(ph + (size_t)(y + 4) * WW + x0, hs[snew], ha[snew]);
                    load_row(pw + (size_t)(y + 4) * WW + x0, vws[snew], vwa[snew]);

                    #pragma unroll
                    for (int j = 0; j < T; ++j) {
                        // fresh 5-tap vertical sums, same order as R3
                        float vs_h = ((hs[k % KS][j] + hs[(k + 1) % KS][j])
                                    + (hs[(k + 2) % KS][j] + hs[(k + 3) % KS][j]))
                                    +  hs[(k + 4) % KS][j];
                        float va_h = ((ha[k % KS][j] + ha[(k + 1) % KS][j])
                                    + (ha[(k + 2) % KS][j] + ha[(k + 3) % KS][j]))
                                    +  ha[(k + 4) % KS][j];
                        float vs_w = ((vws[k % KS][j] + vws[(k + 1) % KS][j])
                                    + (vws[(k + 2) % KS][j] + vws[(k + 3) % KS][j]))
                                    +  vws[(k + 4) % KS][j];
                        float va_w = ((vwa[k % KS][j] + vwa[(k + 1) % KS][j])
                                    + (vwa[(k + 2) % KS][j] + vwa[(k + 3) % KS][j]))
                                    +  vwa[(k + 4) % KS][j];

                        float den_h, den_w;
                        if (__builtin_expect(fabsf(vs_h) < RECOMP_T, 0)) {
                            float s32 = win25_np(ph + (size_t)y * WW + x0 + j);
                            den_h = fabsf(GKC * s32) + EPSC;
                        } else {
                            den_h = fabsf(GKC * vs_h) + EPSC;
                        }
                        if (__builtin_expect(fabsf(vs_w) < RECOMP_T, 0)) {
                            float s32 = win25_np(pw + (size_t)y * WW + x0 + j);
                            den_w = fabsf(GKC * s32) + EPSC;
                        } else {
                            den_w = fabsf(GKC * vs_w) + EPSC;
                        }

                        acc += (GKC * va_h) * __builtin_amdgcn_rcpf(den_h)
                             + (GKC * va_w) * __builtin_amdgcn_rcpf(den_w);
                    }
                }
            }
        }
    }

    // weight: exp(1 - gam[b]), constant per image
    const int b = img / CCH;
    double accd = (double)acc * (double)expf(1.0f - gam[b]);

    // block reduction in f64
    #pragma unroll
    for (int off = 32; off >= 1; off >>= 1)
        accd += __shfl_down(accd, off, 64);

    __shared__ double red[TPB / 64];
    const int lane = threadIdx.x & 63;
    const int wid  = threadIdx.x >> 6;
    if (lane == 0) red[wid] = accd;
    __syncthreads();
    if (threadIdx.x == 0) {
        double t = (red[0] + red[1]) + (red[2] + red[3]);
        partial[(size_t)blockIdx.z * gridDim.y + blockIdx.y] = t;
    }
}

__global__ __launch_bounds__(256)
void rtv_reduce(const double* __restrict__ partial, int n,
                float* __restrict__ out)
{
    double acc = 0.0;
    for (int i = threadIdx.x; i < n; i += 256)
        acc += partial[i];

    #pragma unroll
    for (int off = 32; off >= 1; off >>= 1)
        acc += __shfl_down(acc, off, 64);

    __shared__ double red[4];
    const int lane = threadIdx.x & 63;
    const int wid  = threadIdx.x >> 6;
    if (lane == 0) red[wid] = acc;
    __syncthreads();
    if (threadIdx.x == 0) {
        double tot = (red[0] + red[1]) + (red[2] + red[3]);
        // mean over B*C*OH*OW = 48 * 1020*1020 elements (both terms share N)
        const double N = 48.0 * 1040400.0;
        out[0] = (float)(tot / N);
    }
}

extern "C" void kernel_launch(void* const* d_in, const int* in_sizes, int n_in,
                              void* d_out, int out_size, void* d_ws, size_t ws_size,
                              hipStream_t stream) {
    const float* gh  = (const float*)d_in[0];
    const float* gw  = (const float*)d_in[1];
    const float* gam = (const float*)d_in[2];
    float* out = (float*)d_out;
    double* ws = (double*)d_ws;

    dim3 grid(1, NCHUNK, NIMG);
    rtv_partial<<<grid, TPB, 0, stream>>>(gh, gw, gam, ws);

    const int nparts = NCHUNK * NIMG;   // 768
    rtv_reduce<<<1, 256, 0, stream>>>(ws, nparts, out);
}